// Round 14
// baseline (639.197 us; speedup 1.0000x reference)
//
#include <hip/hip_runtime.h>
#include <math.h>

#define HW 784      // 28*28
#define TSTEPS 30
#define TCHUNK 10   // steps per layer-major chunk (30 = 3 chunks)

struct GaussW { float w[7]; };

// Exact-rounded f32 ops (never fused/contracted) to bitwise-match numpy f32.
__device__ __forceinline__ float fadd(float a, float b) { return __fadd_rn(a, b); }
__device__ __forceinline__ float fmul(float a, float b) { return __fmul_rn(a, b); }
__device__ __forceinline__ float fsub(float a, float b) { return __fsub_rn(a, b); }

#if defined(__has_builtin)
#  if __has_builtin(__builtin_amdgcn_sbfe)
#    define SBFE(x, b) __builtin_amdgcn_sbfe((int)(x), (unsigned)(b), 1u)
#  endif
#  if __has_builtin(__builtin_amdgcn_ubfe)
#    define UBFE(x, o, w) __builtin_amdgcn_ubfe((unsigned)(x), (unsigned)(o), (unsigned)(w))
#  endif
#endif
#ifndef SBFE
#  define SBFE(x, b) (((int)((unsigned)(x) << (31 - (b)))) >> 31)
#endif
#ifndef UBFE
#  define UBFE(x, o, w) (((unsigned)(x) >> (o)) & ((1u << (w)) - 1u))
#endif

// w if bit b of rw set else +0.0f; fadd(acc, this) == fadd(acc, fmul(w, spike))
#define SELW(rw, b, w) __int_as_float(SBFE((rw), (b)) & __float_as_int(w))

// In-wave fence (dmax kernel only).
#define WFENCE() asm volatile("s_waitcnt lgkmcnt(0)" ::: "memory")

__device__ __forceinline__ int refl(int i, int n) {
    if (i < 0) return -i - 1;
    if (i >= n) return 2 * n - 1 - i;
    return i;
}

// Block-wide DoG (fallback path only), bit-exact numpy-f32 order.
// NOTE: dout may alias g (g is dead after stage 2).
__device__ void dog_sample(const float* __restrict__ x, int b, int nbatch,
                           const GaussW gw, float* g, float* t,
                           float* dout, int tid) {
    for (int p = tid; p < HW; p += 256) {
        float acc = fmul(gw.w[0], x[(size_t)refl(b - 3, nbatch) * HW + p]);
        #pragma unroll
        for (int k = 1; k < 7; ++k)
            acc = fadd(acc, fmul(gw.w[k], x[(size_t)refl(b - 3 + k, nbatch) * HW + p]));
        float h = fmul(gw.w[0], acc);
        #pragma unroll
        for (int k = 1; k < 7; ++k)
            h = fadd(h, fmul(gw.w[k], acc));
        g[p] = h;
    }
    __syncthreads();
    for (int p = tid; p < HW; p += 256) {
        int i = p / 28, j = p - (p / 28) * 28;
        float acc = fmul(gw.w[0], g[refl(i - 3, 28) * 28 + j]);
        #pragma unroll
        for (int k = 1; k < 7; ++k)
            acc = fadd(acc, fmul(gw.w[k], g[refl(i - 3 + k, 28) * 28 + j]));
        t[p] = acc;
    }
    __syncthreads();
    for (int p = tid; p < HW; p += 256) {
        int i = p / 28, j = p - (p / 28) * 28;
        float acc = fmul(gw.w[0], t[i * 28 + refl(j - 3, 28)]);
        #pragma unroll
        for (int k = 1; k < 7; ++k)
            acc = fadd(acc, fmul(gw.w[k], t[i * 28 + refl(j - 3 + k, 28)]));
        dout[p] = fabsf(fsub(acc, x[(size_t)b * HW + p]));
    }
    __syncthreads();
}

__global__ void init_kernel(unsigned int* dmax) { *dmax = 0u; }

// Wave-per-sample DoG + global max (+ optional dcache write). No barriers.
template<bool CACHE>
__global__ __launch_bounds__(256) void dmax_kernel(const float* __restrict__ x,
                                                   int nbatch, GaussW gw,
                                                   unsigned int* __restrict__ dmax,
                                                   float* __restrict__ dcache) {
    __shared__ float gS[4][HW];
    __shared__ float tS[4][HW];
    int tid = threadIdx.x;
    int lane = tid & 63, wv = tid >> 6;
    int b = blockIdx.x * 4 + wv;
    int bs = b < nbatch ? b : nbatch - 1;
    float* g = gS[wv];
    float* t = tS[wv];
    const float* xb = x + (size_t)bs * HW;
    const float* xr[7];
    #pragma unroll
    for (int k = 0; k < 7; ++k)
        xr[k] = x + (size_t)refl(bs - 3 + k, nbatch) * HW;

    for (int r = 0; r < 13; ++r) {
        int p = (r << 6) + lane;
        if (p < HW) {
            float acc = fmul(gw.w[0], xr[0][p]);
            #pragma unroll
            for (int k = 1; k < 7; ++k)
                acc = fadd(acc, fmul(gw.w[k], xr[k][p]));
            float h = fmul(gw.w[0], acc);
            #pragma unroll
            for (int k = 1; k < 7; ++k)
                h = fadd(h, fmul(gw.w[k], acc));
            g[p] = h;
        }
    }
    WFENCE();
    for (int r = 0; r < 13; ++r) {
        int p = (r << 6) + lane;
        if (p < HW) {
            int i = p / 28, j = p - (p / 28) * 28;
            float acc = fmul(gw.w[0], g[refl(i - 3, 28) * 28 + j]);
            #pragma unroll
            for (int k = 1; k < 7; ++k)
                acc = fadd(acc, fmul(gw.w[k], g[refl(i - 3 + k, 28) * 28 + j]));
            t[p] = acc;
        }
    }
    WFENCE();
    float mx = 0.f;
    for (int r = 0; r < 13; ++r) {
        int p = (r << 6) + lane;
        if (p < HW) {
            int i = p / 28, j = p - (p / 28) * 28;
            float acc = fmul(gw.w[0], t[i * 28 + refl(j - 3, 28)]);
            #pragma unroll
            for (int k = 1; k < 7; ++k)
                acc = fadd(acc, fmul(gw.w[k], t[i * 28 + refl(j - 3 + k, 28)]));
            float d = fabsf(fsub(acc, xb[p]));
            if (CACHE) dcache[(size_t)bs * HW + p] = d;
            mx = fmaxf(mx, d);
        }
    }
    #pragma unroll
    for (int off = 32; off; off >>= 1) mx = fmaxf(mx, __shfl_down(mx, off, 64));
    if (lane == 0) atomicMax(dmax, __float_as_uint(mx));  // d>=0: bit-max ok
}

// Block-per-sample, layer-major chunks; packed masks, SBFE conv2 (no lut2).
template<bool CACHE>
__global__ __launch_bounds__(256, 5) void sim_kernel(const float* __restrict__ x,
        int nbatch,
        const float* __restrict__ w1g, const float* __restrict__ w2g,
        const float* __restrict__ w3g, GaussW gw,
        const unsigned int* __restrict__ dmaxp,
        const float* __restrict__ dcache,
        float* __restrict__ out) {
    __shared__ __align__(16) float4 lut[512];   // conv1 LUT (4ch); DoG scratch pre-build
    __shared__ float lut3[96];                  // conv3 row LUT [ic][ki][8]
    __shared__ float wts[216];                  // w1(36) | w2(144) | w3(36)
    __shared__ unsigned s1m[TCHUNK * 28];       // layer-1 spike rows
    __shared__ unsigned p1p[TCHUNK * 26];       // pooled-1 packed [13r][2w]: ch2w bits1-13, ch2w+1 bits17-29
    __shared__ unsigned p2p[TCHUNK * 6];        // pooled-2 packed [6r]: ch c bits 6c..6c+5

    int tid = threadIdx.x;
    int b = blockIdx.x;                          // grid = nbatch
    if (b >= nbatch) b = nbatch - 1;

    // ---------------- prologue ----------------
    if (tid < 36)  wts[tid]       = w1g[tid];
    if (tid < 144) wts[36 + tid]  = w2g[tid];
    if (tid < 36)  wts[180 + tid] = w3g[tid];

    float dmaxv = __uint_as_float(*dmaxp);
    float dnr[4];
    if (CACHE) {
        const float* dcb = dcache + (size_t)b * HW;
        #pragma unroll
        for (int k = 0; k < 4; ++k) {
            int p = tid + (k << 8);
            dnr[k] = (p < HW) ? __fdiv_rn(dcb[p], dmaxv) : 0.f;
        }
    } else {
        float* scr = (float*)lut;                // 2048 floats >= 2*784
        dog_sample(x, b, nbatch, gw, scr, scr + HW, scr, tid);  // dout aliases g
        #pragma unroll
        for (int k = 0; k < 4; ++k) {
            int p = tid + (k << 8);
            dnr[k] = (p < HW) ? __fdiv_rn(scr[p], dmaxv) : 0.f;
        }
    }
    __syncthreads();

    // build LUTs + zero all masks
    for (int e = tid; e < 512; e += 256) {
        float a0 = 0.f, a1 = 0.f, a2 = 0.f, a3 = 0.f;
        #pragma unroll
        for (int k = 0; k < 9; ++k) {
            bool bit = (e >> k) & 1;
            a0 = fadd(a0, bit ? wts[k]      : 0.0f);
            a1 = fadd(a1, bit ? wts[9 + k]  : 0.0f);
            a2 = fadd(a2, bit ? wts[18 + k] : 0.0f);
            a3 = fadd(a3, bit ? wts[27 + k] : 0.0f);
        }
        lut[e] = make_float4(a0, a1, a2, a3);
    }
    if (tid < 96) {
        int ric = tid >> 3, idx = tid & 7;
        int ic = ric / 3, ki = ric - ic * 3;
        const float* wb = &wts[180 + ic * 9 + ki * 3];
        float xx = 0.f;
        #pragma unroll
        for (int kk = 0; kk < 3; ++kk)
            xx = fadd(xx, ((idx >> kk) & 1) ? wb[kk] : 0.0f);
        lut3[tid] = xx;
    }
    #pragma unroll
    for (int j = 0; j < 3; ++j) {
        int idx = tid + (j << 8);
        if (idx < 600) {
            if (idx < 280) s1m[idx] = 0u;
            else if (idx < 540) p1p[idx - 280] = 0u;
            else p2p[idx - 540] = 0u;
        }
    }
    __syncthreads();

    // ---------------- fixed per-thread geometry ----------------
    // layer1: pixels e = tid + 256k (k<4; k=3 only tid<16)
    int l1w_[4]; unsigned l1b_[4];
    #pragma unroll
    for (int k = 0; k < 4; ++k) {
        int e = tid + (k << 8); if (e >= HW) e = 0;
        int rw = e / 28;
        l1w_[k] = rw; l1b_[k] = 1u << (e - rw * 28);
    }
    // conv1 quad (tid < 169)
    bool okq = tid < 169;
    int qq1 = okq ? tid : 0;
    int pi1 = qq1 / 13, pj1 = qq1 - pi1 * 13;
    int sr1 = 2 * pi1; unsigned sh1 = (unsigned)(2 * pj1);
    unsigned pb1 = 1u << (pj1 + 1);
    // conv2: exactly 256 items (r7 mapping): rows 0-35 x {5 pairs + 1 single},
    // rows 36-43 x {4 pairs + 1 triple}
    int c2, i2, jp0, ncell2;
    {
        int rowid, sub;
        if (tid < 216) {
            rowid = tid / 6; sub = tid - rowid * 6;
            jp0 = (sub < 5) ? 2 * sub : 10; ncell2 = (sub < 5) ? 2 : 1;
        } else {
            int u = tid - 216; int r5 = u / 5; sub = u - r5 * 5;
            rowid = 36 + r5;
            jp0 = (sub < 4) ? 2 * sub : 8; ncell2 = (sub < 4) ? 2 : 3;
        }
        c2 = rowid / 11; i2 = rowid - c2 * 11;
    }
    unsigned js2 = (unsigned)(jp0 + 1);
    int shf6 = 6 * c2;
    int p2row = (i2 + 1) >> 1;
    unsigned bA = 1u << (jp0 >> 1), bB = 2u << (jp0 >> 1);
    // conv3 (tid < 16)
    int rr3 = (tid >> 2) & 3, cc3 = tid & 3;

    // per-thread conv2 weights (registers)
    float w2r[36];
    #pragma unroll
    for (int m = 0; m < 36; ++m) w2r[m] = wts[36 + c2 * 36 + m];

    // ---------------- membranes (registers) ----------------
    float v2q[16] = {};
    float v3m[3] = {0.f, 0.f, 0.f};
    float v1m[4] = {};
    float v4 = 0.f, pred = 0.f;

    // ---------------- layer-major chunked loop ----------------
    #pragma unroll 1
    for (int c = 0; c < TSTEPS / TCHUNK; ++c) {
        // ==== P1: layer1 x TCHUNK (all threads) ====
        #pragma unroll 1
        for (int tt = 0; tt < TCHUNK; ++tt) {
            unsigned* s1 = s1m + tt * 28;
            #pragma unroll
            for (int k = 0; k < 4; ++k) {
                if (k < 3 || tid < 16) {
                    float v = fadd(v1m[k], dnr[k]);
                    bool spk = v >= 4.5f;
                    v1m[k] = spk ? 0.f : v;
                    if (spk) atomicOr(&s1[l1w_[k]], l1b_[k]);
                }
            }
        }
        __syncthreads();

        // ==== P2: conv1 x TCHUNK (tid<169) | zero p2p (tid>=169) ====
        if (okq) {
            #pragma unroll 1
            for (int tt = 0; tt < TCHUNK; ++tt) {
                const unsigned* s1 = s1m + tt * 28;
                unsigned m0 = s1[sr1], m1 = s1[sr1 + 1], m2 = s1[sr1 + 2], m3 = s1[sr1 + 3];
                unsigned a = UBFE(m0, sh1, 4), bq = UBFE(m1, sh1, 4),
                         cq = UBFE(m2, sh1, 4), dq = UBFE(m3, sh1, 4);
                unsigned a7 = a & 7u, b7 = bq & 7u, c7 = cq & 7u, d7 = dq & 7u;
                unsigned a1 = a >> 1, b1 = bq >> 1, c1 = cq >> 1, d1 = dq >> 1;
                unsigned p00 = a7 | (b7 << 3) | (c7 << 6);
                unsigned p01 = a1 | (b1 << 3) | (c1 << 6);
                unsigned p10 = b7 | (c7 << 3) | (d7 << 6);
                unsigned p11 = b1 | (c1 << 3) | (d1 << 6);
                float4 e00 = lut[p00], e01 = lut[p01], e10 = lut[p10], e11 = lut[p11];
                unsigned cb0 = 0, cb1 = 0, cb2 = 0, cb3 = 0;
                #define C1U(E, ci) { float v; bool s; \
                    v = fadd(v2q[(ci)*4+0], E.x); s = v>=4.5f; v2q[(ci)*4+0] = s?0.f:v; cb0 |= (unsigned)s; \
                    v = fadd(v2q[(ci)*4+1], E.y); s = v>=4.5f; v2q[(ci)*4+1] = s?0.f:v; cb1 |= (unsigned)s; \
                    v = fadd(v2q[(ci)*4+2], E.z); s = v>=4.5f; v2q[(ci)*4+2] = s?0.f:v; cb2 |= (unsigned)s; \
                    v = fadd(v2q[(ci)*4+3], E.w); s = v>=4.5f; v2q[(ci)*4+3] = s?0.f:v; cb3 |= (unsigned)s; }
                C1U(e00, 0) C1U(e01, 1) C1U(e10, 2) C1U(e11, 3)
                #undef C1U
                unsigned* pw = &p1p[(tt * 13 + pi1) * 2];
                unsigned orm0 = (cb0 ? pb1 : 0u) | (cb1 ? (pb1 << 16) : 0u);
                unsigned orm1 = (cb2 ? pb1 : 0u) | (cb3 ? (pb1 << 16) : 0u);
                if (orm0) atomicOr(&pw[0], orm0);
                if (orm1) atomicOr(&pw[1], orm1);
            }
        } else {
            int idx = tid - 169;
            if (idx < TCHUNK * 6) p2p[idx] = 0u;
        }
        __syncthreads();

        // ==== P3: conv2 x TCHUNK (all 256 threads, 1 item each; SBFE taps) ====
        #pragma unroll 1
        for (int tt = 0; tt < TCHUNK; ++tt) {
            const unsigned* pp = &p1p[tt * 26];
            unsigned wq0 = pp[(i2 + 0) * 2], wq0b = pp[(i2 + 0) * 2 + 1];
            unsigned wq1 = pp[(i2 + 1) * 2], wq1b = pp[(i2 + 1) * 2 + 1];
            unsigned wq2 = pp[(i2 + 2) * 2], wq2b = pp[(i2 + 2) * 2 + 1];
            float a0 = 0.f, a1 = 0.f, a2 = 0.f;
            #pragma unroll
            for (int ic = 0; ic < 4; ++ic) {
                unsigned w0r = (ic < 2) ? wq0 : wq0b;
                unsigned w1r = (ic < 2) ? wq1 : wq1b;
                unsigned w2w = (ic < 2) ? wq2 : wq2b;
                unsigned sh = js2 + ((ic & 1) << 4);
                #pragma unroll
                for (int ki = 0; ki < 3; ++ki) {
                    unsigned rw = ((ki == 0) ? w0r : (ki == 1) ? w1r : w2w) >> sh;
                    int w0 = __float_as_int(w2r[ic * 9 + ki * 3 + 0]);
                    int w1 = __float_as_int(w2r[ic * 9 + ki * 3 + 1]);
                    int w2i = __float_as_int(w2r[ic * 9 + ki * 3 + 2]);
                    int m0 = SBFE(rw, 0), m1 = SBFE(rw, 1), m2 = SBFE(rw, 2);
                    a0 = fadd(a0, __int_as_float(m0 & w0));
                    a0 = fadd(a0, __int_as_float(m1 & w1));
                    a0 = fadd(a0, __int_as_float(m2 & w2i));
                    if (ncell2 >= 2) {
                        int m3 = SBFE(rw, 3);
                        a1 = fadd(a1, __int_as_float(m1 & w0));
                        a1 = fadd(a1, __int_as_float(m2 & w1));
                        a1 = fadd(a1, __int_as_float(m3 & w2i));
                        if (ncell2 == 3) {
                            int m4 = SBFE(rw, 4);
                            a2 = fadd(a2, __int_as_float(m2 & w0));
                            a2 = fadd(a2, __int_as_float(m3 & w1));
                            a2 = fadd(a2, __int_as_float(m4 & w2i));
                        }
                    }
                }
            }
            unsigned orm = 0u;
            { float v = fadd(v3m[0], a0); bool s = v >= 1.0f;
              v3m[0] = s ? 0.f : v; if (s) orm |= bA; }
            if (ncell2 >= 2) {
                float v = fadd(v3m[1], a1); bool s = v >= 1.0f;
                v3m[1] = s ? 0.f : v; if (s) orm |= bB;
                if (ncell2 == 3) {
                    float v2 = fadd(v3m[2], a2); bool s2 = v2 >= 1.0f;
                    v3m[2] = s2 ? 0.f : v2; if (s2) orm |= bB;
                }
            }
            if (orm) atomicOr(&p2p[tt * 6 + p2row], orm << shf6);
        }
        __syncthreads();

        // ==== P4: conv3+LIF x TCHUNK (tid<16) | zero s1m+p1p (tid>=16) ====
        if (tid < 16) {
            #pragma unroll 1
            for (int tt = 0; tt < TCHUNK; ++tt) {
                const unsigned* p2 = &p2p[tt * 6];
                unsigned r0 = p2[rr3], r1 = p2[rr3 + 1], r2 = p2[rr3 + 2];
                float acc = 0.f;
                #pragma unroll
                for (int ic = 0; ic < 4; ++ic) {
                    #pragma unroll
                    for (int ki = 0; ki < 3; ++ki) {
                        unsigned row = (ki == 0) ? r0 : (ki == 1) ? r1 : r2;
                        unsigned idx = UBFE(row, 6 * ic + cc3, 3);
                        acc = fadd(acc, lut3[(ic * 3 + ki) * 8 + idx]);
                    }
                }
                v4 = fadd(v4, fmul(fsub(acc, v4), 0.5f));
                if (v4 >= 1.0f) { pred += 1.f; v4 = 0.f; }
            }
        } else {
            #pragma unroll
            for (int j = 0; j < 3; ++j) {
                int idx = (tid - 16) + 240 * j;
                if (idx < 540) {
                    if (idx < 280) s1m[idx] = 0u;
                    else p1p[idx - 280] = 0u;
                }
            }
        }
        __syncthreads();
    }

    if (tid < 16 && blockIdx.x < (unsigned)nbatch)
        out[(size_t)blockIdx.x * 16 + tid] = __fdiv_rn(pred, 30.0f);
}

extern "C" void kernel_launch(void* const* d_in, const int* in_sizes, int n_in,
                              void* d_out, int out_size, void* d_ws, size_t ws_size,
                              hipStream_t stream) {
    const float* x  = (const float*)d_in[0];
    const float* w1 = (const float*)d_in[1];
    const float* w2 = (const float*)d_in[2];
    const float* w3 = (const float*)d_in[3];
    float* out = (float*)d_out;
    unsigned int* dmax = (unsigned int*)d_ws;
    float* dcache = (float*)((char*)d_ws + 16);

    int nbatch = in_sizes[0] / HW;
    size_t need = 16 + (size_t)nbatch * HW * sizeof(float);
    bool cache = ws_size >= need;
    int g4 = (nbatch + 3) / 4;

    // numpy-f32 Gaussian weights: exact f32 steps + correctly-rounded exp
    GaussW gw;
    {
        float fw[7];
        for (int k = 0; k < 7; ++k) {
            float iv = (float)(k - 3);
            float q = iv / 2.0f;
            float e = -0.5f * (q * q);
            fw[k] = (float)exp((double)e);
        }
        float s = 0.0f;
        for (int k = 0; k < 7; ++k) s += fw[k];
        for (int k = 0; k < 7; ++k) gw.w[k] = fw[k] / s;
    }

    hipLaunchKernelGGL(init_kernel, dim3(1), dim3(1), 0, stream, dmax);
    if (cache) {
        hipLaunchKernelGGL(dmax_kernel<true>, dim3(g4), dim3(256), 0, stream,
                           x, nbatch, gw, dmax, dcache);
        hipLaunchKernelGGL(sim_kernel<true>, dim3(nbatch), dim3(256), 0, stream,
                           x, nbatch, w1, w2, w3, gw, dmax, dcache, out);
    } else {
        hipLaunchKernelGGL(dmax_kernel<false>, dim3(g4), dim3(256), 0, stream,
                           x, nbatch, gw, dmax, dcache);
        hipLaunchKernelGGL(sim_kernel<false>, dim3(nbatch), dim3(256), 0, stream,
                           x, nbatch, w1, w2, w3, gw, dmax, dcache, out);
    }
}

// Round 15
// 273.192 us; speedup vs baseline: 2.3397x; 2.3397x over previous
//
#include <hip/hip_runtime.h>
#include <math.h>

#define HW 784      // 28*28
#define TSTEPS 30
#define TCHUNK 10   // steps per layer-major chunk (30 = 3 chunks)

struct GaussW { float w[7]; };

// Exact-rounded f32 ops (never fused/contracted) to bitwise-match numpy f32.
__device__ __forceinline__ float fadd(float a, float b) { return __fadd_rn(a, b); }
__device__ __forceinline__ float fmul(float a, float b) { return __fmul_rn(a, b); }
__device__ __forceinline__ float fsub(float a, float b) { return __fsub_rn(a, b); }

#if defined(__has_builtin)
#  if __has_builtin(__builtin_amdgcn_ubfe)
#    define UBFE(x, o, w) __builtin_amdgcn_ubfe((unsigned)(x), (unsigned)(o), (unsigned)(w))
#  endif
#endif
#ifndef UBFE
#  define UBFE(x, o, w) (((unsigned)(x) >> (o)) & ((1u << (w)) - 1u))
#endif

// In-wave fence (dmax kernel only).
#define WFENCE() asm volatile("s_waitcnt lgkmcnt(0)" ::: "memory")

__device__ __forceinline__ int refl(int i, int n) {
    if (i < 0) return -i - 1;
    if (i >= n) return 2 * n - 1 - i;
    return i;
}

// Block-wide DoG (fallback path only), bit-exact numpy-f32 order.
// dout may alias g (g is dead once stage 3 runs).
__device__ void dog_sample(const float* __restrict__ x, int b, int nbatch,
                           const GaussW gw, float* g, float* t,
                           float* dout, int tid) {
    for (int p = tid; p < HW; p += 256) {
        float acc = fmul(gw.w[0], x[(size_t)refl(b - 3, nbatch) * HW + p]);
        #pragma unroll
        for (int k = 1; k < 7; ++k)
            acc = fadd(acc, fmul(gw.w[k], x[(size_t)refl(b - 3 + k, nbatch) * HW + p]));
        float h = fmul(gw.w[0], acc);
        #pragma unroll
        for (int k = 1; k < 7; ++k)
            h = fadd(h, fmul(gw.w[k], acc));
        g[p] = h;
    }
    __syncthreads();
    for (int p = tid; p < HW; p += 256) {
        int i = p / 28, j = p - (p / 28) * 28;
        float acc = fmul(gw.w[0], g[refl(i - 3, 28) * 28 + j]);
        #pragma unroll
        for (int k = 1; k < 7; ++k)
            acc = fadd(acc, fmul(gw.w[k], g[refl(i - 3 + k, 28) * 28 + j]));
        t[p] = acc;
    }
    __syncthreads();
    for (int p = tid; p < HW; p += 256) {
        int i = p / 28, j = p - (p / 28) * 28;
        float acc = fmul(gw.w[0], t[i * 28 + refl(j - 3, 28)]);
        #pragma unroll
        for (int k = 1; k < 7; ++k)
            acc = fadd(acc, fmul(gw.w[k], t[i * 28 + refl(j - 3 + k, 28)]));
        dout[p] = fabsf(fsub(acc, x[(size_t)b * HW + p]));
    }
    __syncthreads();
}

__global__ void init_kernel(unsigned int* dmax) { *dmax = 0u; }

// Wave-per-sample DoG + global max (+ optional dcache write). No barriers.
template<bool CACHE>
__global__ __launch_bounds__(256) void dmax_kernel(const float* __restrict__ x,
                                                   int nbatch, GaussW gw,
                                                   unsigned int* __restrict__ dmax,
                                                   float* __restrict__ dcache) {
    __shared__ float gS[4][HW];
    __shared__ float tS[4][HW];
    int tid = threadIdx.x;
    int lane = tid & 63, wv = tid >> 6;
    int b = blockIdx.x * 4 + wv;
    int bs = b < nbatch ? b : nbatch - 1;
    float* g = gS[wv];
    float* t = tS[wv];
    const float* xb = x + (size_t)bs * HW;
    const float* xr[7];
    #pragma unroll
    for (int k = 0; k < 7; ++k)
        xr[k] = x + (size_t)refl(bs - 3 + k, nbatch) * HW;

    for (int r = 0; r < 13; ++r) {
        int p = (r << 6) + lane;
        if (p < HW) {
            float acc = fmul(gw.w[0], xr[0][p]);
            #pragma unroll
            for (int k = 1; k < 7; ++k)
                acc = fadd(acc, fmul(gw.w[k], xr[k][p]));
            float h = fmul(gw.w[0], acc);
            #pragma unroll
            for (int k = 1; k < 7; ++k)
                h = fadd(h, fmul(gw.w[k], acc));
            g[p] = h;
        }
    }
    WFENCE();
    for (int r = 0; r < 13; ++r) {
        int p = (r << 6) + lane;
        if (p < HW) {
            int i = p / 28, j = p - (p / 28) * 28;
            float acc = fmul(gw.w[0], g[refl(i - 3, 28) * 28 + j]);
            #pragma unroll
            for (int k = 1; k < 7; ++k)
                acc = fadd(acc, fmul(gw.w[k], g[refl(i - 3 + k, 28) * 28 + j]));
            t[p] = acc;
        }
    }
    WFENCE();
    float mx = 0.f;
    for (int r = 0; r < 13; ++r) {
        int p = (r << 6) + lane;
        if (p < HW) {
            int i = p / 28, j = p - (p / 28) * 28;
            float acc = fmul(gw.w[0], t[i * 28 + refl(j - 3, 28)]);
            #pragma unroll
            for (int k = 1; k < 7; ++k)
                acc = fadd(acc, fmul(gw.w[k], t[i * 28 + refl(j - 3 + k, 28)]));
            float d = fabsf(fsub(acc, xb[p]));
            if (CACHE) dcache[(size_t)bs * HW + p] = d;
            mx = fmaxf(mx, d);
        }
    }
    #pragma unroll
    for (int off = 32; off; off >>= 1) mx = fmaxf(mx, __shfl_down(mx, off, 64));
    if (lane == 0) atomicMax(dmax, __float_as_uint(mx));  // d>=0: bit-max ok
}

// Block-per-sample, layer-major chunks; packed masks + lut2 conv2 (r13 base).
template<bool CACHE>
__global__ __launch_bounds__(256, 6) void sim_kernel(const float* __restrict__ x,
        int nbatch,
        const float* __restrict__ w1g, const float* __restrict__ w2g,
        const float* __restrict__ w3g, GaussW gw,
        const unsigned int* __restrict__ dmaxp,
        const float* __restrict__ dcache,
        float* __restrict__ out) {
    __shared__ __align__(16) float4 lut[512];   // conv1 LUT (4ch); DoG scratch pre-build
    __shared__ __align__(8)  float2 lut2[768];  // conv2 row-pair LUT [cout][ic][ki][16]
    __shared__ float lut3[96];                  // conv3 row LUT [ic][ki][8]
    __shared__ float wts[216];                  // w1(36) | w2(144) | w3(36)
    __shared__ unsigned s1m[TCHUNK * 28];       // layer-1 spike rows
    __shared__ __align__(8) unsigned p1p[TCHUNK * 26]; // pooled-1 packed [13r][2w]:
                                                //  word w: ch 2w bits 1-13, ch 2w+1 bits 17-29
    __shared__ unsigned p2p[TCHUNK * 6];        // pooled-2 packed [6r]: ch c bits 6c..6c+5

    int tid = threadIdx.x;
    int b = blockIdx.x;                          // grid = nbatch
    if (b >= nbatch) b = nbatch - 1;

    // ---------------- prologue ----------------
    if (tid < 36)  wts[tid]       = w1g[tid];
    if (tid < 144) wts[36 + tid]  = w2g[tid];
    if (tid < 36)  wts[180 + tid] = w3g[tid];

    float dmaxv = __uint_as_float(*dmaxp);
    float dnr[4];
    if (CACHE) {
        const float* dcb = dcache + (size_t)b * HW;
        #pragma unroll
        for (int k = 0; k < 4; ++k) {
            int p = tid + (k << 8);
            dnr[k] = (p < HW) ? __fdiv_rn(dcb[p], dmaxv) : 0.f;
        }
    } else {
        float* scr = (float*)lut;                // 2048 floats >= 2*784
        dog_sample(x, b, nbatch, gw, scr, scr + HW, scr, tid);  // dout aliases g
        #pragma unroll
        for (int k = 0; k < 4; ++k) {
            int p = tid + (k << 8);
            dnr[k] = (p < HW) ? __fdiv_rn(scr[p], dmaxv) : 0.f;
        }
    }
    __syncthreads();

    // build LUTs + zero all masks
    for (int e = tid; e < 512; e += 256) {
        float a0 = 0.f, a1 = 0.f, a2 = 0.f, a3 = 0.f;
        #pragma unroll
        for (int k = 0; k < 9; ++k) {
            bool bit = (e >> k) & 1;
            a0 = fadd(a0, bit ? wts[k]      : 0.0f);
            a1 = fadd(a1, bit ? wts[9 + k]  : 0.0f);
            a2 = fadd(a2, bit ? wts[18 + k] : 0.0f);
            a3 = fadd(a3, bit ? wts[27 + k] : 0.0f);
        }
        lut[e] = make_float4(a0, a1, a2, a3);
    }
    for (int e = tid; e < 768; e += 256) {
        int rowIdx = e >> 4, idx = e & 15;
        int cout = rowIdx / 12, rem = rowIdx - cout * 12;
        int ic = rem / 3, ki = rem - ic * 3;
        const float* wb = &wts[36 + cout * 36 + ic * 9 + ki * 3];
        float xx = 0.f, yy = 0.f;
        #pragma unroll
        for (int kk = 0; kk < 3; ++kk) {
            xx = fadd(xx, ((idx >> kk) & 1) ? wb[kk] : 0.0f);
            yy = fadd(yy, ((idx >> (kk + 1)) & 1) ? wb[kk] : 0.0f);
        }
        lut2[e] = make_float2(xx, yy);
    }
    if (tid < 96) {
        int ric = tid >> 3, idx = tid & 7;
        int ic = ric / 3, ki = ric - ic * 3;
        const float* wb = &wts[180 + ic * 9 + ki * 3];
        float xx = 0.f;
        #pragma unroll
        for (int kk = 0; kk < 3; ++kk)
            xx = fadd(xx, ((idx >> kk) & 1) ? wb[kk] : 0.0f);
        lut3[tid] = xx;
    }
    #pragma unroll
    for (int j = 0; j < 3; ++j) {
        int idx = tid + (j << 8);
        if (idx < 600) {
            if (idx < 280) s1m[idx] = 0u;
            else if (idx < 540) p1p[idx - 280] = 0u;
            else p2p[idx - 540] = 0u;
        }
    }
    __syncthreads();

    // ---------------- fixed per-thread geometry ----------------
    // layer1: pixels e = tid + 256k (k<4; k=3 only tid<16)
    int l1w_[4]; unsigned l1b_[4];
    #pragma unroll
    for (int k = 0; k < 4; ++k) {
        int e = tid + (k << 8); if (e >= HW) e = 0;
        int rw = e / 28;
        l1w_[k] = rw; l1b_[k] = 1u << (e - rw * 28);
    }
    // conv1 quad (tid < 169)
    bool okq = tid < 169;
    int qq1 = okq ? tid : 0;
    int pi1 = qq1 / 13, pj1 = qq1 - pi1 * 13;
    int sr1 = 2 * pi1; unsigned sh1 = (unsigned)(2 * pj1);
    unsigned pb1 = 1u << (pj1 + 1);
    // conv2 (r13 mapping): item A = tid; item B = 256+(tid-248) for tids >= 248
    //   item m: row=m/6 (0..43), sub=m%6; j0=(sub<5)?2*sub:10 (pair / single)
    bool hasB = tid >= 248;
    int i2cA, lb2A, p2wA; unsigned js2A, shA, b20A, b21A;
    int i2cB, lb2B, p2wB; unsigned js2B, shB, b20B, b21B;
    {
        int m = tid;
        int row = m / 6, sub = m - row * 6;
        int j0 = (sub < 5) ? 2 * sub : 10;
        int c = row / 11, i2 = row - c * 11;
        i2cA = i2; js2A = (unsigned)(j0 + 1) + ((unsigned)(c & 1) << 4);
        lb2A = c * 192; shA = 6u * (unsigned)c;
        p2wA = (i2 + 1) >> 1;
        b20A = 1u << (j0 >> 1);
        b21A = (sub < 5) ? (2u << (j0 >> 1)) : 0u;
        int wA = c >> 1; i2cA = i2cA * 2 + wA;   // fold word index into row addr? no —
        i2cA = i2;                                // keep row; word chosen at read
        m = hasB ? 256 + (tid - 248) : 0;
        row = m / 6; sub = m - row * 6;
        j0 = (sub < 5) ? 2 * sub : 10;
        c = row / 11; i2 = row - c * 11;
        i2cB = i2; js2B = (unsigned)(j0 + 1) + ((unsigned)(c & 1) << 4);
        lb2B = c * 192; shB = 6u * (unsigned)c;
        p2wB = (i2 + 1) >> 1;
        b20B = 1u << (j0 >> 1);
        b21B = (sub < 5) ? (2u << (j0 >> 1)) : 0u;
    }
    int cwA = 0, cwB = 0;
    { int m = tid; int row = m / 6; cwA = (row / 11) >> 1; }
    { int m = hasB ? 256 + (tid - 248) : 0; int row = m / 6; cwB = (row / 11) >> 1; }
    // conv3 (tid < 16)
    int rr3 = (tid >> 2) & 3, cc3 = tid & 3;

    // ---------------- membranes (registers) ----------------
    float v2q[16] = {};
    float v3A[2] = {0.f, 0.f}, v3B[2] = {0.f, 0.f};
    float v1m[4] = {};
    float v4 = 0.f, pred = 0.f;

    // ---------------- layer-major chunked loop ----------------
    #pragma unroll 1
    for (int c = 0; c < TSTEPS / TCHUNK; ++c) {
        // ==== P1: layer1 x TCHUNK (all threads) ====
        #pragma unroll 1
        for (int tt = 0; tt < TCHUNK; ++tt) {
            unsigned* s1 = s1m + tt * 28;
            #pragma unroll
            for (int k = 0; k < 4; ++k) {
                if (k < 3 || tid < 16) {
                    float v = fadd(v1m[k], dnr[k]);
                    bool spk = v >= 4.5f;
                    v1m[k] = spk ? 0.f : v;
                    if (spk) atomicOr(&s1[l1w_[k]], l1b_[k]);
                }
            }
        }
        __syncthreads();

        // ==== P2: conv1 x TCHUNK (tid<169) | zero p2p (tid>=169) ====
        if (okq) {
            #pragma unroll 1
            for (int tt = 0; tt < TCHUNK; ++tt) {
                const unsigned* s1 = s1m + tt * 28;
                unsigned m0 = s1[sr1], m1 = s1[sr1 + 1], m2 = s1[sr1 + 2], m3 = s1[sr1 + 3];
                unsigned a = UBFE(m0, sh1, 4), bq = UBFE(m1, sh1, 4),
                         cq = UBFE(m2, sh1, 4), dq = UBFE(m3, sh1, 4);
                unsigned a7 = a & 7u, b7 = bq & 7u, c7 = cq & 7u, d7 = dq & 7u;
                unsigned a1 = a >> 1, b1 = bq >> 1, c1 = cq >> 1, d1 = dq >> 1;
                unsigned p00 = a7 | (b7 << 3) | (c7 << 6);
                unsigned p01 = a1 | (b1 << 3) | (c1 << 6);
                unsigned p10 = b7 | (c7 << 3) | (d7 << 6);
                unsigned p11 = b1 | (c1 << 3) | (d1 << 6);
                float4 e00 = lut[p00], e01 = lut[p01], e10 = lut[p10], e11 = lut[p11];
                unsigned cb0 = 0, cb1 = 0, cb2 = 0, cb3 = 0;
                #define C1U(E, ci) { float v; bool s; \
                    v = fadd(v2q[(ci)*4+0], E.x); s = v>=4.5f; v2q[(ci)*4+0] = s?0.f:v; cb0 |= (unsigned)s; \
                    v = fadd(v2q[(ci)*4+1], E.y); s = v>=4.5f; v2q[(ci)*4+1] = s?0.f:v; cb1 |= (unsigned)s; \
                    v = fadd(v2q[(ci)*4+2], E.z); s = v>=4.5f; v2q[(ci)*4+2] = s?0.f:v; cb2 |= (unsigned)s; \
                    v = fadd(v2q[(ci)*4+3], E.w); s = v>=4.5f; v2q[(ci)*4+3] = s?0.f:v; cb3 |= (unsigned)s; }
                C1U(e00, 0) C1U(e01, 1) C1U(e10, 2) C1U(e11, 3)
                #undef C1U
                unsigned* pw = &p1p[(tt * 13 + pi1) * 2];
                unsigned orm0 = (cb0 ? pb1 : 0u) | (cb1 ? (pb1 << 16) : 0u);
                unsigned orm1 = (cb2 ? pb1 : 0u) | (cb3 ? (pb1 << 16) : 0u);
                if (orm0) atomicOr(&pw[0], orm0);
                if (orm1) atomicOr(&pw[1], orm1);
            }
        } else {
            int idx = tid - 169;
            if (idx < TCHUNK * 6) p2p[idx] = 0u;
        }
        __syncthreads();

        // ==== P3: conv2 x TCHUNK (lut2 gather; packed p1 rows) ====
        #pragma unroll 1
        for (int tt = 0; tt < TCHUNK; ++tt) {
            const uint2* pp = (const uint2*)&p1p[tt * 26];
            unsigned* p2w = &p2p[tt * 6];
            {   // item A
                uint2 r0 = pp[i2cA], r1 = pp[i2cA + 1], r2 = pp[i2cA + 2];
                float accA = 0.f, accB = 0.f;
                #pragma unroll
                for (int ic = 0; ic < 4; ++ic) {
                    unsigned w0 = (cwA == 0) ? ((ic < 2) ? r0.x : r0.y)
                                             : ((ic < 2) ? r0.x : r0.y);
                    // word select by channel pair of THIS item's cout is fixed:
                    // channels ic are the INPUT channels -> word = ic>>1 always.
                    unsigned rw0 = (ic < 2) ? r0.x : r0.y;
                    unsigned rw1 = (ic < 2) ? r1.x : r1.y;
                    unsigned rw2 = (ic < 2) ? r2.x : r2.y;
                    unsigned fo = (unsigned)(js2A & 15u) + ((unsigned)(ic & 1) << 4);
                    (void)w0;
                    #pragma unroll
                    for (int ki = 0; ki < 3; ++ki) {
                        unsigned row = (ki == 0) ? rw0 : (ki == 1) ? rw1 : rw2;
                        unsigned idx = UBFE(row, fo, 4);
                        float2 e = lut2[lb2A + (ic * 3 + ki) * 16 + idx];
                        accA = fadd(accA, e.x);
                        accB = fadd(accB, e.y);
                    }
                }
                float va = fadd(v3A[0], accA);
                float vb = fadd(v3A[1], accB);
                bool sa = va >= 1.0f, sb = vb >= 1.0f;
                v3A[0] = sa ? 0.f : va; v3A[1] = sb ? 0.f : vb;
                unsigned orm = (sa ? b20A : 0u) | (sb ? b21A : 0u);
                if (orm) atomicOr(&p2w[p2wA], orm << shA);
            }
            if (hasB) {   // item B
                uint2 r0 = pp[i2cB], r1 = pp[i2cB + 1], r2 = pp[i2cB + 2];
                float accA = 0.f, accB = 0.f;
                #pragma unroll
                for (int ic = 0; ic < 4; ++ic) {
                    unsigned rw0 = (ic < 2) ? r0.x : r0.y;
                    unsigned rw1 = (ic < 2) ? r1.x : r1.y;
                    unsigned rw2 = (ic < 2) ? r2.x : r2.y;
                    unsigned fo = (unsigned)(js2B & 15u) + ((unsigned)(ic & 1) << 4);
                    #pragma unroll
                    for (int ki = 0; ki < 3; ++ki) {
                        unsigned row = (ki == 0) ? rw0 : (ki == 1) ? rw1 : rw2;
                        unsigned idx = UBFE(row, fo, 4);
                        float2 e = lut2[lb2B + (ic * 3 + ki) * 16 + idx];
                        accA = fadd(accA, e.x);
                        accB = fadd(accB, e.y);
                    }
                }
                float va = fadd(v3B[0], accA);
                float vb = fadd(v3B[1], accB);
                bool sa = va >= 1.0f, sb = vb >= 1.0f;
                v3B[0] = sa ? 0.f : va; v3B[1] = sb ? 0.f : vb;
                unsigned orm = (sa ? b20B : 0u) | (sb ? b21B : 0u);
                if (orm) atomicOr(&p2w[p2wB], orm << shB);
            }
        }
        __syncthreads();

        // ==== P4: conv3+LIF x TCHUNK (tid<16) | zero s1m+p1p (tid>=16) ====
        if (tid < 16) {
            #pragma unroll 1
            for (int tt = 0; tt < TCHUNK; ++tt) {
                const unsigned* p2 = &p2p[tt * 6];
                unsigned r0 = p2[rr3], r1 = p2[rr3 + 1], r2 = p2[rr3 + 2];
                float acc = 0.f;
                #pragma unroll
                for (int ic = 0; ic < 4; ++ic) {
                    #pragma unroll
                    for (int ki = 0; ki < 3; ++ki) {
                        unsigned row = (ki == 0) ? r0 : (ki == 1) ? r1 : r2;
                        unsigned idx = UBFE(row, 6 * ic + cc3, 3);
                        acc = fadd(acc, lut3[(ic * 3 + ki) * 8 + idx]);
                    }
                }
                v4 = fadd(v4, fmul(fsub(acc, v4), 0.5f));
                if (v4 >= 1.0f) { pred += 1.f; v4 = 0.f; }
            }
        } else {
            #pragma unroll
            for (int j = 0; j < 3; ++j) {
                int idx = (tid - 16) + 240 * j;
                if (idx < 540) {
                    if (idx < 280) s1m[idx] = 0u;
                    else p1p[idx - 280] = 0u;
                }
            }
        }
        __syncthreads();
    }

    if (tid < 16 && blockIdx.x < (unsigned)nbatch)
        out[(size_t)blockIdx.x * 16 + tid] = __fdiv_rn(pred, 30.0f);
}

extern "C" void kernel_launch(void* const* d_in, const int* in_sizes, int n_in,
                              void* d_out, int out_size, void* d_ws, size_t ws_size,
                              hipStream_t stream) {
    const float* x  = (const float*)d_in[0];
    const float* w1 = (const float*)d_in[1];
    const float* w2 = (const float*)d_in[2];
    const float* w3 = (const float*)d_in[3];
    float* out = (float*)d_out;
    unsigned int* dmax = (unsigned int*)d_ws;
    float* dcache = (float*)((char*)d_ws + 16);

    int nbatch = in_sizes[0] / HW;
    size_t need = 16 + (size_t)nbatch * HW * sizeof(float);
    bool cache = ws_size >= need;
    int g4 = (nbatch + 3) / 4;

    // numpy-f32 Gaussian weights: exact f32 steps + correctly-rounded exp
    GaussW gw;
    {
        float fw[7];
        for (int k = 0; k < 7; ++k) {
            float iv = (float)(k - 3);
            float q = iv / 2.0f;
            float e = -0.5f * (q * q);
            fw[k] = (float)exp((double)e);
        }
        float s = 0.0f;
        for (int k = 0; k < 7; ++k) s += fw[k];
        for (int k = 0; k < 7; ++k) gw.w[k] = fw[k] / s;
    }

    hipLaunchKernelGGL(init_kernel, dim3(1), dim3(1), 0, stream, dmax);
    if (cache) {
        hipLaunchKernelGGL(dmax_kernel<true>, dim3(g4), dim3(256), 0, stream,
                           x, nbatch, gw, dmax, dcache);
        hipLaunchKernelGGL(sim_kernel<true>, dim3(nbatch), dim3(256), 0, stream,
                           x, nbatch, w1, w2, w3, gw, dmax, dcache, out);
    } else {
        hipLaunchKernelGGL(dmax_kernel<false>, dim3(g4), dim3(256), 0, stream,
                           x, nbatch, gw, dmax, dcache);
        hipLaunchKernelGGL(sim_kernel<false>, dim3(nbatch), dim3(256), 0, stream,
                           x, nbatch, w1, w2, w3, gw, dmax, dcache, out);
    }
}

// Round 16
// 230.572 us; speedup vs baseline: 2.7722x; 1.1848x over previous
//
#include <hip/hip_runtime.h>
#include <math.h>

#define HW 784      // 28*28
#define TSTEPS 30   // single chunk: all 30 steps' masks resident in LDS

struct GaussW { float w[7]; };

// Exact-rounded f32 ops (never fused/contracted) to bitwise-match numpy f32.
__device__ __forceinline__ float fadd(float a, float b) { return __fadd_rn(a, b); }
__device__ __forceinline__ float fmul(float a, float b) { return __fmul_rn(a, b); }
__device__ __forceinline__ float fsub(float a, float b) { return __fsub_rn(a, b); }

#if defined(__has_builtin)
#  if __has_builtin(__builtin_amdgcn_ubfe)
#    define UBFE(x, o, w) __builtin_amdgcn_ubfe((unsigned)(x), (unsigned)(o), (unsigned)(w))
#  endif
#endif
#ifndef UBFE
#  define UBFE(x, o, w) (((unsigned)(x) >> (o)) & ((1u << (w)) - 1u))
#endif

// In-wave fence (dmax kernel only).
#define WFENCE() asm volatile("s_waitcnt lgkmcnt(0)" ::: "memory")

__device__ __forceinline__ int refl(int i, int n) {
    if (i < 0) return -i - 1;
    if (i >= n) return 2 * n - 1 - i;
    return i;
}

// Block-wide DoG (fallback path only), bit-exact numpy-f32 order.
// dout may alias g (g is dead once stage 3 runs).
__device__ void dog_sample(const float* __restrict__ x, int b, int nbatch,
                           const GaussW gw, float* g, float* t,
                           float* dout, int tid) {
    for (int p = tid; p < HW; p += 256) {
        float acc = fmul(gw.w[0], x[(size_t)refl(b - 3, nbatch) * HW + p]);
        #pragma unroll
        for (int k = 1; k < 7; ++k)
            acc = fadd(acc, fmul(gw.w[k], x[(size_t)refl(b - 3 + k, nbatch) * HW + p]));
        float h = fmul(gw.w[0], acc);
        #pragma unroll
        for (int k = 1; k < 7; ++k)
            h = fadd(h, fmul(gw.w[k], acc));
        g[p] = h;
    }
    __syncthreads();
    for (int p = tid; p < HW; p += 256) {
        int i = p / 28, j = p - (p / 28) * 28;
        float acc = fmul(gw.w[0], g[refl(i - 3, 28) * 28 + j]);
        #pragma unroll
        for (int k = 1; k < 7; ++k)
            acc = fadd(acc, fmul(gw.w[k], g[refl(i - 3 + k, 28) * 28 + j]));
        t[p] = acc;
    }
    __syncthreads();
    for (int p = tid; p < HW; p += 256) {
        int i = p / 28, j = p - (p / 28) * 28;
        float acc = fmul(gw.w[0], t[i * 28 + refl(j - 3, 28)]);
        #pragma unroll
        for (int k = 1; k < 7; ++k)
            acc = fadd(acc, fmul(gw.w[k], t[i * 28 + refl(j - 3 + k, 28)]));
        dout[p] = fabsf(fsub(acc, x[(size_t)b * HW + p]));
    }
    __syncthreads();
}

__global__ void init_kernel(unsigned int* dmax) { *dmax = 0u; }

// Wave-per-sample DoG + global max (+ optional dcache write). No barriers.
template<bool CACHE>
__global__ __launch_bounds__(256) void dmax_kernel(const float* __restrict__ x,
                                                   int nbatch, GaussW gw,
                                                   unsigned int* __restrict__ dmax,
                                                   float* __restrict__ dcache) {
    __shared__ float gS[4][HW];
    __shared__ float tS[4][HW];
    int tid = threadIdx.x;
    int lane = tid & 63, wv = tid >> 6;
    int b = blockIdx.x * 4 + wv;
    int bs = b < nbatch ? b : nbatch - 1;
    float* g = gS[wv];
    float* t = tS[wv];
    const float* xb = x + (size_t)bs * HW;
    const float* xr[7];
    #pragma unroll
    for (int k = 0; k < 7; ++k)
        xr[k] = x + (size_t)refl(bs - 3 + k, nbatch) * HW;

    for (int r = 0; r < 13; ++r) {
        int p = (r << 6) + lane;
        if (p < HW) {
            float acc = fmul(gw.w[0], xr[0][p]);
            #pragma unroll
            for (int k = 1; k < 7; ++k)
                acc = fadd(acc, fmul(gw.w[k], xr[k][p]));
            float h = fmul(gw.w[0], acc);
            #pragma unroll
            for (int k = 1; k < 7; ++k)
                h = fadd(h, fmul(gw.w[k], acc));
            g[p] = h;
        }
    }
    WFENCE();
    for (int r = 0; r < 13; ++r) {
        int p = (r << 6) + lane;
        if (p < HW) {
            int i = p / 28, j = p - (p / 28) * 28;
            float acc = fmul(gw.w[0], g[refl(i - 3, 28) * 28 + j]);
            #pragma unroll
            for (int k = 1; k < 7; ++k)
                acc = fadd(acc, fmul(gw.w[k], g[refl(i - 3 + k, 28) * 28 + j]));
            t[p] = acc;
        }
    }
    WFENCE();
    float mx = 0.f;
    for (int r = 0; r < 13; ++r) {
        int p = (r << 6) + lane;
        if (p < HW) {
            int i = p / 28, j = p - (p / 28) * 28;
            float acc = fmul(gw.w[0], t[i * 28 + refl(j - 3, 28)]);
            #pragma unroll
            for (int k = 1; k < 7; ++k)
                acc = fadd(acc, fmul(gw.w[k], t[i * 28 + refl(j - 3 + k, 28)]));
            float d = fabsf(fsub(acc, xb[p]));
            if (CACHE) dcache[(size_t)bs * HW + p] = d;
            mx = fmaxf(mx, d);
        }
    }
    #pragma unroll
    for (int off = 32; off; off >>= 1) mx = fmaxf(mx, __shfl_down(mx, off, 64));
    if (lane == 0) atomicMax(dmax, __float_as_uint(mx));  // d>=0: bit-max ok
}

// Block-per-sample, single-chunk layer-major: 4 main barriers, ballot layer1.
template<bool CACHE>
__global__ __launch_bounds__(256, 6) void sim_kernel(const float* __restrict__ x,
        int nbatch,
        const float* __restrict__ w1g, const float* __restrict__ w2g,
        const float* __restrict__ w3g, GaussW gw,
        const unsigned int* __restrict__ dmaxp,
        const float* __restrict__ dcache,
        float* __restrict__ out) {
    __shared__ __align__(16) float4 lut[512];   // conv1 LUT (4ch); DoG scratch pre-build
    __shared__ __align__(8)  float2 lut2[768];  // conv2 row-pair LUT [cout][ic][ki][16]
    __shared__ float lut3[96];                  // conv3 row LUT [ic][ki][8]
    __shared__ float wts[216];                  // w1(36) | w2(144) | w3(36)
    __shared__ unsigned s1m[TSTEPS * 28];       // layer-1 spike rows, all steps
    __shared__ __align__(8) unsigned p1p[TSTEPS * 26]; // pooled-1 packed [13r][2w]:
                                                //  word w: ch 2w bits 1-13, ch 2w+1 bits 17-29
    __shared__ unsigned p2p[TSTEPS * 6];        // pooled-2 packed [6r]: ch c bits 6c..6c+5

    int tid = threadIdx.x;
    int lane = tid & 63, wv = tid >> 6;
    int b = blockIdx.x;                          // grid = nbatch
    if (b >= nbatch) b = nbatch - 1;

    // ---------------- prologue ----------------
    if (tid < 36)  wts[tid]       = w1g[tid];
    if (tid < 144) wts[36 + tid]  = w2g[tid];
    if (tid < 36)  wts[180 + tid] = w3g[tid];

    // layer1 geometry: wave wv owns row-pairs r = wv + 4k (k<4; k=3 only wv<2).
    // lane l<56 -> pixel 56r + l (rows 2r, 2r+1).
    float dmaxv = __uint_as_float(*dmaxp);
    float dnr[4];
    if (CACHE) {
        const float* dcb = dcache + (size_t)b * HW;
        #pragma unroll
        for (int k = 0; k < 4; ++k) {
            int r = wv + 4 * k;
            int p = 56 * r + (lane < 56 ? lane : 0);
            float d = (r < 14) ? dcb[p] : 0.f;
            dnr[k] = (lane < 56 && r < 14) ? __fdiv_rn(d, dmaxv) : 0.f;
        }
    } else {
        float* scr = (float*)lut;                // 2048 floats >= 2*784
        dog_sample(x, b, nbatch, gw, scr, scr + HW, scr, tid);  // dout aliases g
        #pragma unroll
        for (int k = 0; k < 4; ++k) {
            int r = wv + 4 * k;
            int p = 56 * r + (lane < 56 ? lane : 0);
            float d = (r < 14) ? scr[p] : 0.f;
            dnr[k] = (lane < 56 && r < 14) ? __fdiv_rn(d, dmaxv) : 0.f;
        }
    }
    __syncthreads();

    // build LUTs + zero mask buffers (once; no re-zero needed, single chunk)
    for (int e = tid; e < 512; e += 256) {
        float a0 = 0.f, a1 = 0.f, a2 = 0.f, a3 = 0.f;
        #pragma unroll
        for (int k = 0; k < 9; ++k) {
            bool bit = (e >> k) & 1;
            a0 = fadd(a0, bit ? wts[k]      : 0.0f);
            a1 = fadd(a1, bit ? wts[9 + k]  : 0.0f);
            a2 = fadd(a2, bit ? wts[18 + k] : 0.0f);
            a3 = fadd(a3, bit ? wts[27 + k] : 0.0f);
        }
        lut[e] = make_float4(a0, a1, a2, a3);
    }
    for (int e = tid; e < 768; e += 256) {
        int rowIdx = e >> 4, idx = e & 15;
        int cout = rowIdx / 12, rem = rowIdx - cout * 12;
        int ic = rem / 3, ki = rem - ic * 3;
        const float* wb = &wts[36 + cout * 36 + ic * 9 + ki * 3];
        float xx = 0.f, yy = 0.f;
        #pragma unroll
        for (int kk = 0; kk < 3; ++kk) {
            xx = fadd(xx, ((idx >> kk) & 1) ? wb[kk] : 0.0f);
            yy = fadd(yy, ((idx >> (kk + 1)) & 1) ? wb[kk] : 0.0f);
        }
        lut2[e] = make_float2(xx, yy);
    }
    if (tid < 96) {
        int ric = tid >> 3, idx = tid & 7;
        int ic = ric / 3, ki = ric - ic * 3;
        const float* wb = &wts[180 + ic * 9 + ki * 3];
        float xx = 0.f;
        #pragma unroll
        for (int kk = 0; kk < 3; ++kk)
            xx = fadd(xx, ((idx >> kk) & 1) ? wb[kk] : 0.0f);
        lut3[tid] = xx;
    }
    #pragma unroll
    for (int j = 0; j < 8; ++j) {
        int idx = tid + (j << 8);
        if (idx < TSTEPS * 60) {                 // 840 + 780 + 180 = 1800
            if (idx < TSTEPS * 28) s1m[idx] = 0u;
            else if (idx < TSTEPS * 54) p1p[idx - TSTEPS * 28] = 0u;
            else p2p[idx - TSTEPS * 54] = 0u;
        }
    }
    __syncthreads();

    // ---------------- fixed per-thread geometry ----------------
    // conv1 quad (tid < 169)
    bool okq = tid < 169;
    int qq1 = okq ? tid : 0;
    int pi1 = qq1 / 13, pj1 = qq1 - pi1 * 13;
    int sr1 = 2 * pi1; unsigned sh1 = (unsigned)(2 * pj1);
    unsigned pb1 = 1u << (pj1 + 1);
    // conv2: item A = tid; item B = 256+(tid-248) for tids >= 248
    //   item m: row=m/6 (0..43), sub=m%6; j0=(sub<5)?2*sub:10 (pair / single)
    bool hasB = tid >= 248;
    int i2A, lbA, pwA; unsigned jsA, shA, bA0, bA1;
    int i2B, lbB, pwB; unsigned jsB, shB, bB0, bB1;
    {
        int m = tid;
        int row = m / 6, sub = m - row * 6;
        int j0 = (sub < 5) ? 2 * sub : 10;
        int c = row / 11, i2 = row - c * 11;
        i2A = i2; jsA = (unsigned)(j0 + 1); lbA = c * 192; shA = 6u * (unsigned)c;
        pwA = (i2 + 1) >> 1;
        bA0 = 1u << (j0 >> 1);
        bA1 = (sub < 5) ? (2u << (j0 >> 1)) : 0u;
        m = hasB ? 256 + (tid - 248) : 0;
        row = m / 6; sub = m - row * 6;
        j0 = (sub < 5) ? 2 * sub : 10;
        c = row / 11; i2 = row - c * 11;
        i2B = i2; jsB = (unsigned)(j0 + 1); lbB = c * 192; shB = 6u * (unsigned)c;
        pwB = (i2 + 1) >> 1;
        bB0 = 1u << (j0 >> 1);
        bB1 = (sub < 5) ? (2u << (j0 >> 1)) : 0u;
    }
    // conv3 (tid < 16)
    int rr3 = (tid >> 2) & 3, cc3 = tid & 3;

    // ---------------- membranes (registers) ----------------
    float v2q[16] = {};
    float v3A[2] = {0.f, 0.f}, v3B[2] = {0.f, 0.f};
    float v1m[4] = {};
    float v4 = 0.f, pred = 0.f;

    // ==== P1: layer1 x 30 (ballot; lanes 0/1 plain-store the 2 row words) ====
    #pragma unroll 1
    for (int tt = 0; tt < TSTEPS; ++tt) {
        unsigned* s1 = s1m + tt * 28;
        #pragma unroll
        for (int k = 0; k < 4; ++k) {
            if (k < 3 || wv < 2) {
                int r = wv + 4 * k;
                float v = fadd(v1m[k], dnr[k]);
                bool spk = (lane < 56) && (v >= 4.5f);
                v1m[k] = spk ? 0.f : v;
                unsigned long long bal = __ballot(spk);
                if (lane < 2)
                    s1[2 * r + lane] = (unsigned)(lane ? (bal >> 28) : bal) & 0x0FFFFFFFu;
            }
        }
    }
    __syncthreads();

    // ==== P2: conv1 x 30 (tid < 169) ====
    if (okq) {
        #pragma unroll 1
        for (int tt = 0; tt < TSTEPS; ++tt) {
            const unsigned* s1 = s1m + tt * 28;
            unsigned m0 = s1[sr1], m1 = s1[sr1 + 1], m2 = s1[sr1 + 2], m3 = s1[sr1 + 3];
            unsigned a = UBFE(m0, sh1, 4), bq = UBFE(m1, sh1, 4),
                     cq = UBFE(m2, sh1, 4), dq = UBFE(m3, sh1, 4);
            unsigned a7 = a & 7u, b7 = bq & 7u, c7 = cq & 7u, d7 = dq & 7u;
            unsigned a1 = a >> 1, b1 = bq >> 1, c1 = cq >> 1, d1 = dq >> 1;
            unsigned p00 = a7 | (b7 << 3) | (c7 << 6);
            unsigned p01 = a1 | (b1 << 3) | (c1 << 6);
            unsigned p10 = b7 | (c7 << 3) | (d7 << 6);
            unsigned p11 = b1 | (c1 << 3) | (d1 << 6);
            float4 e00 = lut[p00], e01 = lut[p01], e10 = lut[p10], e11 = lut[p11];
            unsigned cb0 = 0, cb1 = 0, cb2 = 0, cb3 = 0;
            #define C1U(E, ci) { float v; bool s; \
                v = fadd(v2q[(ci)*4+0], E.x); s = v>=4.5f; v2q[(ci)*4+0] = s?0.f:v; cb0 |= (unsigned)s; \
                v = fadd(v2q[(ci)*4+1], E.y); s = v>=4.5f; v2q[(ci)*4+1] = s?0.f:v; cb1 |= (unsigned)s; \
                v = fadd(v2q[(ci)*4+2], E.z); s = v>=4.5f; v2q[(ci)*4+2] = s?0.f:v; cb2 |= (unsigned)s; \
                v = fadd(v2q[(ci)*4+3], E.w); s = v>=4.5f; v2q[(ci)*4+3] = s?0.f:v; cb3 |= (unsigned)s; }
            C1U(e00, 0) C1U(e01, 1) C1U(e10, 2) C1U(e11, 3)
            #undef C1U
            unsigned* pw = &p1p[(tt * 13 + pi1) * 2];
            unsigned orm0 = (cb0 ? pb1 : 0u) | (cb1 ? (pb1 << 16) : 0u);
            unsigned orm1 = (cb2 ? pb1 : 0u) | (cb3 ? (pb1 << 16) : 0u);
            if (orm0) atomicOr(&pw[0], orm0);
            if (orm1) atomicOr(&pw[1], orm1);
        }
    }
    __syncthreads();

    // ==== P3: conv2 x 30 (item A all threads; item B tids 248-255) ====
    #pragma unroll 1
    for (int tt = 0; tt < TSTEPS; ++tt) {
        const uint2* pp = (const uint2*)&p1p[tt * 26];
        unsigned* p2w = &p2p[tt * 6];
        {   // item A
            uint2 r0 = pp[i2A], r1 = pp[i2A + 1], r2 = pp[i2A + 2];
            float accA = 0.f, accB = 0.f;
            #pragma unroll
            for (int ic = 0; ic < 4; ++ic) {
                unsigned rw0 = (ic < 2) ? r0.x : r0.y;
                unsigned rw1 = (ic < 2) ? r1.x : r1.y;
                unsigned rw2 = (ic < 2) ? r2.x : r2.y;
                unsigned fo = jsA + ((unsigned)(ic & 1) << 4);
                #pragma unroll
                for (int ki = 0; ki < 3; ++ki) {
                    unsigned row = (ki == 0) ? rw0 : (ki == 1) ? rw1 : rw2;
                    unsigned idx = UBFE(row, fo, 4);
                    float2 e = lut2[lbA + (ic * 3 + ki) * 16 + idx];
                    accA = fadd(accA, e.x);
                    accB = fadd(accB, e.y);
                }
            }
            float va = fadd(v3A[0], accA);
            float vb = fadd(v3A[1], accB);
            bool sa = va >= 1.0f, sb = vb >= 1.0f;
            v3A[0] = sa ? 0.f : va; v3A[1] = sb ? 0.f : vb;
            unsigned orm = (sa ? bA0 : 0u) | (sb ? bA1 : 0u);
            if (orm) atomicOr(&p2w[pwA], orm << shA);
        }
        if (hasB) {   // item B
            uint2 r0 = pp[i2B], r1 = pp[i2B + 1], r2 = pp[i2B + 2];
            float accA = 0.f, accB = 0.f;
            #pragma unroll
            for (int ic = 0; ic < 4; ++ic) {
                unsigned rw0 = (ic < 2) ? r0.x : r0.y;
                unsigned rw1 = (ic < 2) ? r1.x : r1.y;
                unsigned rw2 = (ic < 2) ? r2.x : r2.y;
                unsigned fo = jsB + ((unsigned)(ic & 1) << 4);
                #pragma unroll
                for (int ki = 0; ki < 3; ++ki) {
                    unsigned row = (ki == 0) ? rw0 : (ki == 1) ? rw1 : rw2;
                    unsigned idx = UBFE(row, fo, 4);
                    float2 e = lut2[lbB + (ic * 3 + ki) * 16 + idx];
                    accA = fadd(accA, e.x);
                    accB = fadd(accB, e.y);
                }
            }
            float va = fadd(v3B[0], accA);
            float vb = fadd(v3B[1], accB);
            bool sa = va >= 1.0f, sb = vb >= 1.0f;
            v3B[0] = sa ? 0.f : va; v3B[1] = sb ? 0.f : vb;
            unsigned orm = (sa ? bB0 : 0u) | (sb ? bB1 : 0u);
            if (orm) atomicOr(&p2w[pwB], orm << shB);
        }
    }
    __syncthreads();

    // ==== P4: conv3 + LIF x 30 (tid < 16) ====
    if (tid < 16) {
        #pragma unroll 1
        for (int tt = 0; tt < TSTEPS; ++tt) {
            const unsigned* p2 = &p2p[tt * 6];
            unsigned r0 = p2[rr3], r1 = p2[rr3 + 1], r2 = p2[rr3 + 2];
            float acc = 0.f;
            #pragma unroll
            for (int ic = 0; ic < 4; ++ic) {
                #pragma unroll
                for (int ki = 0; ki < 3; ++ki) {
                    unsigned row = (ki == 0) ? r0 : (ki == 1) ? r1 : r2;
                    unsigned idx = UBFE(row, 6 * ic + cc3, 3);
                    acc = fadd(acc, lut3[(ic * 3 + ki) * 8 + idx]);
                }
            }
            v4 = fadd(v4, fmul(fsub(acc, v4), 0.5f));
            if (v4 >= 1.0f) { pred += 1.f; v4 = 0.f; }
        }
        if (blockIdx.x < (unsigned)nbatch)
            out[(size_t)blockIdx.x * 16 + tid] = __fdiv_rn(pred, 30.0f);
    }
}

extern "C" void kernel_launch(void* const* d_in, const int* in_sizes, int n_in,
                              void* d_out, int out_size, void* d_ws, size_t ws_size,
                              hipStream_t stream) {
    const float* x  = (const float*)d_in[0];
    const float* w1 = (const float*)d_in[1];
    const float* w2 = (const float*)d_in[2];
    const float* w3 = (const float*)d_in[3];
    float* out = (float*)d_out;
    unsigned int* dmax = (unsigned int*)d_ws;
    float* dcache = (float*)((char*)d_ws + 16);

    int nbatch = in_sizes[0] / HW;
    size_t need = 16 + (size_t)nbatch * HW * sizeof(float);
    bool cache = ws_size >= need;
    int g4 = (nbatch + 3) / 4;

    // numpy-f32 Gaussian weights: exact f32 steps + correctly-rounded exp
    GaussW gw;
    {
        float fw[7];
        for (int k = 0; k < 7; ++k) {
            float iv = (float)(k - 3);
            float q = iv / 2.0f;
            float e = -0.5f * (q * q);
            fw[k] = (float)exp((double)e);
        }
        float s = 0.0f;
        for (int k = 0; k < 7; ++k) s += fw[k];
        for (int k = 0; k < 7; ++k) gw.w[k] = fw[k] / s;
    }

    hipLaunchKernelGGL(init_kernel, dim3(1), dim3(1), 0, stream, dmax);
    if (cache) {
        hipLaunchKernelGGL(dmax_kernel<true>, dim3(g4), dim3(256), 0, stream,
                           x, nbatch, gw, dmax, dcache);
        hipLaunchKernelGGL(sim_kernel<true>, dim3(nbatch), dim3(256), 0, stream,
                           x, nbatch, w1, w2, w3, gw, dmax, dcache, out);
    } else {
        hipLaunchKernelGGL(dmax_kernel<false>, dim3(g4), dim3(256), 0, stream,
                           x, nbatch, gw, dmax, dcache);
        hipLaunchKernelGGL(sim_kernel<false>, dim3(nbatch), dim3(256), 0, stream,
                           x, nbatch, w1, w2, w3, gw, dmax, dcache, out);
    }
}